// Round 1
// 720.180 us; speedup vs baseline: 1.1777x; 1.1777x over previous
//
#include <hip/hip_runtime.h>

#define NR 64          // NX == NY
#define NH 256         // H
#define NP1 65
#define TSTRIDE 68     // padded row stride for transposed staging tiles (multiple of 4)
#define NITER 20

__device__ __forceinline__ float dot4(float4 a, float4 b) {
  return a.x * b.x + a.y * b.y + a.z * b.z + a.w * b.w;
}

__global__ __launch_bounds__(256, 4)
void sinkhorn_kernel(const float* __restrict__ x, const float* __restrict__ y,
                     const float* __restrict__ gam, const float* __restrict__ bet,
                     const float* __restrict__ wdb, const float* __restrict__ bdb,
                     float* __restrict__ out_match, float* __restrict__ out_score)
{
  const int b    = blockIdx.x;
  const int t    = threadIdx.x;
  const int lane = t & 63;
  const int wvid = t >> 6;      // wave 0..3
  const int ti   = t >> 4;      // 0..15
  const int tj   = t & 15;      // 0..15
  const int i0   = ti * 4, j0 = tj * 4;

  // staging: xsT[64][68] | ysT[64][68]; after matmul the front aliases as the
  // tiny per-wave v-exchange buffers vp[2][4][64] + vp64[2][4].
  __shared__ __align__(16) float s_buf[2 * NR * TSTRIDE];   // 8704 floats = 34.8 KB
  __shared__ __align__(16) float s_gw[NH];
  __shared__ __align__(16) float s_sx[NR], s_ax[NR], s_sy[NR], s_ay[NR];
  __shared__ float s_red[8];
  __shared__ float s_S12[2];

  float* xsT  = s_buf;
  float* ysT  = s_buf + NR * TSTRIDE;
  float* vp   = s_buf;          // [2][4][64]  (aliases xsT, dead after matmul)
  float* vp64 = s_buf + 512;    // [2][4]

  const float norm_c  = -4.852030263919617f;    // -log(128); exp(norm_c) = 1/128
  const float logmu64 = -0.6931471805599453f;   // log(64)-log(128) = -log2; exp = 0.5

  // ---------------- phase 0: gw = gamma*w, S1 = sum(gw), S2 = sum(beta*w)+b
  {
    float gv = gam[t];
    float wv = wdb[t];
    float p1 = gv * wv;
    float p2 = bet[t] * wv;
    s_gw[t] = p1;
    #pragma unroll
    for (int o = 1; o < 64; o <<= 1) { p1 += __shfl_xor(p1, o); p2 += __shfl_xor(p2, o); }
    if (lane == 0) { s_red[wvid * 2] = p1; s_red[wvid * 2 + 1] = p2; }
  }
  __syncthreads();
  if (t == 0) {
    s_S12[0] = s_red[0] + s_red[2] + s_red[4] + s_red[6];
    s_S12[1] = s_red[1] + s_red[3] + s_red[5] + s_red[7] + bdb[0];
  }

  // ---------------- phase 1: staged (transposed, XOR-swizzled) load + stats + matmul
  float acc[4][4] = {};
  float xsum[4] = {}, xsq[4] = {}, xdg[4] = {};
  float ysum[4] = {}, ysq[4] = {}, ydg[4] = {};

  const size_t gbase = (size_t)b * NR * NH;
  const int lh4 = tj * 4;      // h-offset within 64-float chunk

  for (int ch = 0; ch < 4; ++ch) {
    __syncthreads();   // previous chunk's matmul reads done before overwrite
    const float4 gw4 = *(const float4*)(s_gw + ch * 64 + lh4);
    #pragma unroll
    for (int j = 0; j < 4; ++j) {
      const int row = ti + 16 * j;
      // element (kk=h, i=row) stored at kk*68 + 4*((i>>2)^(kk>>2)) + (i&3);
      // here kk>>2 == tj for all 4 kk's of this thread -> one wcol per j.
      const int wcol = ((((row >> 2) ^ tj) & 15) << 2) + (row & 3);
      const float4 xv = *(const float4*)(x + gbase + (size_t)row * NH + ch * 64 + lh4);
      xsum[j] += xv.x + xv.y + xv.z + xv.w;
      xsq[j]  += dot4(xv, xv);
      xdg[j]  += dot4(xv, gw4);
      xsT[(lh4 + 0) * TSTRIDE + wcol] = xv.x;
      xsT[(lh4 + 1) * TSTRIDE + wcol] = xv.y;
      xsT[(lh4 + 2) * TSTRIDE + wcol] = xv.z;
      xsT[(lh4 + 3) * TSTRIDE + wcol] = xv.w;
      const float4 yv = *(const float4*)(y + gbase + (size_t)row * NH + ch * 64 + lh4);
      ysum[j] += yv.x + yv.y + yv.z + yv.w;
      ysq[j]  += dot4(yv, yv);
      ydg[j]  += dot4(yv, gw4);
      ysT[(lh4 + 0) * TSTRIDE + wcol] = yv.x;
      ysT[(lh4 + 1) * TSTRIDE + wcol] = yv.y;
      ysT[(lh4 + 2) * TSTRIDE + wcol] = yv.z;
      ysT[(lh4 + 3) * TSTRIDE + wcol] = yv.w;
    }
    __syncthreads();
    #pragma unroll 4
    for (int k = 0; k < 64; ++k) {
      const int kb = k >> 2;
      const float4 a4 = *(const float4*)(xsT + k * TSTRIDE + (((ti ^ kb) & 15) << 2));
      const float4 b4 = *(const float4*)(ysT + k * TSTRIDE + (((tj ^ kb) & 15) << 2));
      acc[0][0] += a4.x * b4.x; acc[0][1] += a4.x * b4.y; acc[0][2] += a4.x * b4.z; acc[0][3] += a4.x * b4.w;
      acc[1][0] += a4.y * b4.x; acc[1][1] += a4.y * b4.y; acc[1][2] += a4.y * b4.z; acc[1][3] += a4.y * b4.w;
      acc[2][0] += a4.z * b4.x; acc[2][1] += a4.z * b4.y; acc[2][2] += a4.z * b4.z; acc[2][3] += a4.z * b4.w;
      acc[3][0] += a4.w * b4.x; acc[3][1] += a4.w * b4.y; acc[3][2] += a4.w * b4.z; acc[3][3] += a4.w * b4.w;
    }
  }

  // reduce stats across the 16 lanes sharing the same row set
  #pragma unroll
  for (int o = 1; o < 16; o <<= 1) {
    #pragma unroll
    for (int j = 0; j < 4; ++j) {
      xsum[j] += __shfl_xor(xsum[j], o);
      xsq[j]  += __shfl_xor(xsq[j], o);
      xdg[j]  += __shfl_xor(xdg[j], o);
      ysum[j] += __shfl_xor(ysum[j], o);
      ysq[j]  += __shfl_xor(ysq[j], o);
      ydg[j]  += __shfl_xor(ydg[j], o);
    }
  }
  {
    if (tj == 0) {
      const float S1 = s_S12[0], S2 = s_S12[1];
      #pragma unroll
      for (int j = 0; j < 4; ++j) {
        const int r = ti + 16 * j;
        float mu   = xsum[j] * (1.0f / NH);
        float var  = xsq[j] * (1.0f / NH) - mu * mu;
        float rstd = rsqrtf(var + 1e-5f);
        s_ax[r] = tanhf(rstd * (xdg[j] - mu * S1) + S2);
        s_sx[r] = 1.0f / fmaxf(sqrtf(xsq[j]), 1e-12f);
        mu   = ysum[j] * (1.0f / NH);
        var  = ysq[j] * (1.0f / NH) - mu * mu;
        rstd = rsqrtf(var + 1e-5f);
        s_ay[r] = tanhf(rstd * (ydg[j] - mu * S1) + S2);
        s_sy[r] = 1.0f / fmaxf(sqrtf(ysq[j]), 1e-12f);
      }
    }
  }
  __syncthreads();   // stats visible; all staging LDS reads done -> safe to alias vp

  // ---------------- C = couplings/reg and E = exp(C), entirely in registers
  const float4 sx4 = *(const float4*)(s_sx + i0);
  const float4 sy4 = *(const float4*)(s_sy + j0);
  const float4 ax4 = *(const float4*)(s_ax + i0);
  const float4 ay4 = *(const float4*)(s_ay + j0);
  const float sxr[4] = {sx4.x, sx4.y, sx4.z, sx4.w};
  const float syc[4] = {sy4.x, sy4.y, sy4.z, sy4.w};
  float C[4][4], E[4][4];
  #pragma unroll
  for (int r = 0; r < 4; ++r) {
    #pragma unroll
    for (int c = 0; c < 4; ++c) {
      C[r][c] = acc[r][c] * sxr[r] * syc[c] * 10.0f;   // /REG
      E[r][c] = __expf(C[r][c]);
    }
  }
  const float exi64[4] = {__expf(10.0f * ax4.x), __expf(10.0f * ax4.y),
                          __expf(10.0f * ax4.z), __expf(10.0f * ax4.w)};
  const float ey64[4]  = {__expf(10.0f * ay4.x), __expf(10.0f * ay4.y),
                          __expf(10.0f * ay4.z), __expf(10.0f * ay4.w)};

  // ---------------- Sinkhorn: 20 iterations, all state in registers.
  // u-row sums reduce over the 16 tj lanes; v-col sums reduce over ti via
  // shfl(16/32) + a 1 KB double-buffered cross-wave exchange (1 barrier/iter).
  float ev_c[4] = {1.0f, 1.0f, 1.0f, 1.0f};
  float ev64 = 1.0f;
  float eu_r[4];
  float eu64 = 1.0f;
  float su_s[4], p64_s, sv_s[4], rs_s;   // last-iteration sums for final u/v logs
  int bufo = 0;

  #pragma unroll 2
  for (int it = 0; it < NITER; ++it) {
    // ---- u update (exp domain): eu_i = exp(norm)/sum_j E[i][j] ev[j]
    float s0 = E[0][0] * ev_c[0] + E[0][1] * ev_c[1] + E[0][2] * ev_c[2] + E[0][3] * ev_c[3];
    float s1 = E[1][0] * ev_c[0] + E[1][1] * ev_c[1] + E[1][2] * ev_c[2] + E[1][3] * ev_c[3];
    float s2 = E[2][0] * ev_c[0] + E[2][1] * ev_c[1] + E[2][2] * ev_c[2] + E[2][3] * ev_c[3];
    float s3 = E[3][0] * ev_c[0] + E[3][1] * ev_c[1] + E[3][2] * ev_c[2] + E[3][3] * ev_c[3];
    float p64 = ey64[0] * ev_c[0] + ey64[1] * ev_c[1] + ey64[2] * ev_c[2] + ey64[3] * ev_c[3];
    #pragma unroll
    for (int o = 1; o < 16; o <<= 1) {
      s0  += __shfl_xor(s0, o);
      s1  += __shfl_xor(s1, o);
      s2  += __shfl_xor(s2, o);
      s3  += __shfl_xor(s3, o);
      p64 += __shfl_xor(p64, o);
    }
    su_s[0] = s0 + exi64[0] * ev64;
    su_s[1] = s1 + exi64[1] * ev64;
    su_s[2] = s2 + exi64[2] * ev64;
    su_s[3] = s3 + exi64[3] * ev64;
    p64_s = p64;
    eu_r[0] = 0.0078125f * __builtin_amdgcn_rcpf(su_s[0]);
    eu_r[1] = 0.0078125f * __builtin_amdgcn_rcpf(su_s[1]);
    eu_r[2] = 0.0078125f * __builtin_amdgcn_rcpf(su_s[2]);
    eu_r[3] = 0.0078125f * __builtin_amdgcn_rcpf(su_s[3]);
    eu64    = 0.5f       * __builtin_amdgcn_rcpf(p64);

    // ---- v update: ev_j = exp(norm)/sum_i E[i][j] eu[i]
    float q0 = E[0][0] * eu_r[0] + E[1][0] * eu_r[1] + E[2][0] * eu_r[2] + E[3][0] * eu_r[3];
    float q1 = E[0][1] * eu_r[0] + E[1][1] * eu_r[1] + E[2][1] * eu_r[2] + E[3][1] * eu_r[3];
    float q2 = E[0][2] * eu_r[0] + E[1][2] * eu_r[1] + E[2][2] * eu_r[2] + E[3][2] * eu_r[3];
    float q3 = E[0][3] * eu_r[0] + E[1][3] * eu_r[1] + E[2][3] * eu_r[2] + E[3][3] * eu_r[3];
    float r64 = exi64[0] * eu_r[0] + exi64[1] * eu_r[1] + exi64[2] * eu_r[2] + exi64[3] * eu_r[3];
    #pragma unroll
    for (int o = 16; o < 64; o <<= 1) {
      q0  += __shfl_xor(q0, o);
      q1  += __shfl_xor(q1, o);
      q2  += __shfl_xor(q2, o);
      q3  += __shfl_xor(q3, o);
      r64 += __shfl_xor(r64, o);
    }
    if ((t & 48) == 0) {   // one 16-lane slice per wave writes the wave partial
      *(float4*)(vp + (bufo * 4 + wvid) * 64 + j0) = make_float4(q0, q1, q2, q3);
      if (tj == 0) vp64[bufo * 4 + wvid] = r64;
    }
    __syncthreads();
    float sv0 = 0.0f, sv1 = 0.0f, sv2 = 0.0f, sv3 = 0.0f;
    #pragma unroll
    for (int w = 0; w < 4; ++w) {
      const float4 qq = *(const float4*)(vp + (bufo * 4 + w) * 64 + j0);
      sv0 += qq.x; sv1 += qq.y; sv2 += qq.z; sv3 += qq.w;
    }
    const float4 rr4 = *(const float4*)(vp64 + bufo * 4);
    rs_s = rr4.x + rr4.y + rr4.z + rr4.w;
    sv_s[0] = sv0 + ey64[0] * eu64;
    sv_s[1] = sv1 + ey64[1] * eu64;
    sv_s[2] = sv2 + ey64[2] * eu64;
    sv_s[3] = sv3 + ey64[3] * eu64;
    ev_c[0] = 0.0078125f * __builtin_amdgcn_rcpf(sv_s[0]);
    ev_c[1] = 0.0078125f * __builtin_amdgcn_rcpf(sv_s[1]);
    ev_c[2] = 0.0078125f * __builtin_amdgcn_rcpf(sv_s[2]);
    ev_c[3] = 0.0078125f * __builtin_amdgcn_rcpf(sv_s[3]);
    ev64    = 0.5f       * __builtin_amdgcn_rcpf(rs_s);
    bufo ^= 1;
  }

  // final u, v in log domain (only needed for the output)
  float u_r[4], v_c[4];
  #pragma unroll
  for (int r = 0; r < 4; ++r) u_r[r] = norm_c - __logf(su_s[r]);
  #pragma unroll
  for (int c = 0; c < 4; ++c) v_c[c] = norm_c - __logf(sv_s[c]);
  const float u64 = logmu64 - __logf(p64_s);
  const float v64 = logmu64 - __logf(rs_s);

  // ---------------- outputs: matching (b,65,65) straight from registers + fused score
  float sacc = 0.0f;
  const size_t mbase = (size_t)b * (size_t)(NP1 * NP1);
  #pragma unroll
  for (int r = 0; r < 4; ++r) {
    const float m0 = C[r][0] + u_r[r] + v_c[0] - norm_c;
    const float m1 = C[r][1] + u_r[r] + v_c[1] - norm_c;
    const float m2 = C[r][2] + u_r[r] + v_c[2] - norm_c;
    const float m3 = C[r][3] + u_r[r] + v_c[3] - norm_c;
    *(float4*)(out_match + mbase + (size_t)(i0 + r) * NP1 + j0) = make_float4(m0, m1, m2, m3);
    sacc += __expf(m0) * C[r][0] + __expf(m1) * C[r][1]
          + __expf(m2) * C[r][2] + __expf(m3) * C[r][3];   // scores/temp == C (reg==temp)
  }
  if (t < 16) {   // dustbin row 64: these threads own cols j0..j0+3 (ti==0 group)
    const float4 ayv = *(const float4*)(s_ay + j0);
    *(float4*)(out_match + mbase + (size_t)64 * NP1 + j0) = make_float4(
        10.0f * ayv.x + u64 + v_c[0] - norm_c,
        10.0f * ayv.y + u64 + v_c[1] - norm_c,
        10.0f * ayv.z + u64 + v_c[2] - norm_c,
        10.0f * ayv.w + u64 + v_c[3] - norm_c);
  }
  if (tj == 0) {  // dustbin col 64: these threads own rows i0..i0+3
    const float4 axv = *(const float4*)(s_ax + i0);
    out_match[mbase + (size_t)(i0 + 0) * NP1 + 64] = 10.0f * axv.x + u_r[0] + v64 - norm_c;
    out_match[mbase + (size_t)(i0 + 1) * NP1 + 64] = 10.0f * axv.y + u_r[1] + v64 - norm_c;
    out_match[mbase + (size_t)(i0 + 2) * NP1 + 64] = 10.0f * axv.z + u_r[2] + v64 - norm_c;
    out_match[mbase + (size_t)(i0 + 3) * NP1 + 64] = 10.0f * axv.w + u_r[3] + v64 - norm_c;
  }
  if (t == 0) {
    out_match[mbase + (size_t)64 * NP1 + 64] = -1000.0f + u64 + v64 - norm_c;
  }

  #pragma unroll
  for (int o = 1; o < 64; o <<= 1) sacc += __shfl_xor(sacc, o);
  if (lane == 0) s_red[wvid] = sacc;
  __syncthreads();
  if (t == 0) out_score[b] = s_red[0] + s_red[1] + s_red[2] + s_red[3];
}

extern "C" void kernel_launch(void* const* d_in, const int* in_sizes, int n_in,
                              void* d_out, int out_size, void* d_ws, size_t ws_size,
                              hipStream_t stream) {
  const float* x   = (const float*)d_in[0];
  const float* y   = (const float*)d_in[1];
  const float* gam = (const float*)d_in[2];
  const float* bet = (const float*)d_in[3];
  const float* wdb = (const float*)d_in[4];
  const float* bdb = (const float*)d_in[5];
  float* out_match = (float*)d_out;
  float* out_score = (float*)d_out + (size_t)4096 * 4225;
  sinkhorn_kernel<<<4096, 256, 0, stream>>>(x, y, gam, bet, wdb, bdb, out_match, out_score);
}